// Round 1
// baseline (1130.710 us; speedup 1.0000x reference)
//
#include <hip/hip_runtime.h>
#include <cstddef>

// Fused 8-layer MLP (NeRF-style), MI355X gfx950.
// Strategy: f16 MFMA 16x16x32, M=out-features, N=points. Activations live in
// LDS [point][feature] with XOR-swizzled 16B chunks; weights pre-packed in
// A-fragment order by a prep kernel into d_ws. 128 points/block, 4 waves,
// each wave = 64 feats x 128 points = 4x8 MFMA tiles (128 acc VGPRs).
// LDS: act 64KB + input-cache 16KB = 80KB -> 2 blocks/CU.

typedef _Float16 half8 __attribute__((ext_vector_type(8)));
typedef _Float16 half4 __attribute__((ext_vector_type(4)));
typedef float floatx4 __attribute__((ext_vector_type(4)));

#define N_POINTS 524288
#define IN_DIM   63
#define P_TILE   128
#define N_BLOCKS (N_POINTS / P_TILE)   // 4096

// Global k-step bases per layer in the packed-weight buffer.
// KS per layer: L0=2 (K=64 padded), L1..3=8, L4=10 (K=320 padded), L5..7=8.
// cum: 0,2,10,18,26,36,44,52  (total 60 ksteps; 60*16*512 = 491520 halfs)

// ---------------- prep: pack weights into A-fragment order, f16 -------------
// Element layout: Wp[((gks*16 + mt)*64 + lane)*8 + i] = A[m][k] = W_l[k][m]
// with m = 16*mt + (lane&15), k = 32*(gks-cum_l) + (lane>>4)*8 + i.
__global__ void mlp_prep(_Float16* __restrict__ Wp,
    const float* __restrict__ W0, const float* __restrict__ W1,
    const float* __restrict__ W2, const float* __restrict__ W3,
    const float* __restrict__ W4, const float* __restrict__ W5,
    const float* __restrict__ W6, const float* __restrict__ W7)
{
    int e    = blockIdx.x * 256 + threadIdx.x;   // 0 .. 491519
    int gks  = e >> 13;                          // /8192
    int rem  = e & 8191;
    int mt   = rem >> 9;
    int r3   = rem & 511;
    int lane = r3 >> 3;
    int i    = r3 & 7;
    int m    = mt * 16 + (lane & 15);

    int l, kb;
    if      (gks <  2) { l = 0; kb = gks;      }
    else if (gks < 10) { l = 1; kb = gks - 2;  }
    else if (gks < 18) { l = 2; kb = gks - 10; }
    else if (gks < 26) { l = 3; kb = gks - 18; }
    else if (gks < 36) { l = 4; kb = gks - 26; }
    else if (gks < 44) { l = 5; kb = gks - 36; }
    else if (gks < 52) { l = 6; kb = gks - 44; }
    else               { l = 7; kb = gks - 52; }
    int k = kb * 32 + (lane >> 4) * 8 + i;

    const float* W = (l==0)?W0:(l==1)?W1:(l==2)?W2:(l==3)?W3:(l==4)?W4:(l==5)?W5:(l==6)?W6:W7;
    float v;
    if (l == 0)      v = (k < IN_DIM) ? W[k * 256 + m] : 0.f;
    else if (l == 4) v = (k < IN_DIM) ? W[k * 256 + m]
                        : (k == IN_DIM ? 0.f : W[(k - 1) * 256 + m]);
    else             v = W[k * 256 + m];
    Wp[e] = (_Float16)v;
}

// ---------------- main fused kernel -----------------------------------------
__device__ __forceinline__ void a_frags(const _Float16* __restrict__ Wp,
                                        int gks, int wv, int lane, half8 (&a)[4])
{
    const _Float16* base = Wp + ((size_t)gks * 16 + (size_t)wv * 4) * 512 + lane * 8;
#pragma unroll
    for (int mt = 0; mt < 4; ++mt)
        a[mt] = *(const half8*)(base + mt * 512);
}

// B frags from LDS. rowHalfs = 64 (input cache) or 256 (activations).
// chunk index for lane = cbase + quad, XOR-swizzled by (point & 7) == (ln & 7).
__device__ __forceinline__ void b_frags(const _Float16* __restrict__ src,
                                        int rowHalfs, int cbase, int ln, int q,
                                        half8 (&b)[8])
{
    int ch = ((cbase + q) ^ (ln & 7)) << 3;                 // halfs within row
    const _Float16* base = src + ln * rowHalfs + ch;
    int step = 16 * rowHalfs;                               // next n-tile (16 points)
#pragma unroll
    for (int nt = 0; nt < 8; ++nt)
        b[nt] = *(const half8*)(base + nt * step);
}

__device__ __forceinline__ void mfma_step(const half8 (&a)[4], const half8 (&b)[8],
                                          floatx4 (&acc)[4][8])
{
#pragma unroll
    for (int nt = 0; nt < 8; ++nt)
#pragma unroll
        for (int mt = 0; mt < 4; ++mt)
            acc[mt][nt] = __builtin_amdgcn_mfma_f32_16x16x32_f16(a[mt], b[nt], acc[mt][nt], 0, 0, 0);
}

template<int KS, int KS_IN, bool RELU, bool LAST>
__device__ __forceinline__ void layer_fn(const _Float16* __restrict__ Wp, int gbase,
                                         const float* __restrict__ bias,
                                         const _Float16* __restrict__ inL,
                                         _Float16* __restrict__ actL,
                                         float* __restrict__ out, int pbase,
                                         int wv, int lane)
{
    const int ln = lane & 15, q = lane >> 4;
    floatx4 acc[4][8];
#pragma unroll
    for (int mt = 0; mt < 4; ++mt)
#pragma unroll
        for (int nt = 0; nt < 8; ++nt)
            acc[mt][nt] = (floatx4){0.f, 0.f, 0.f, 0.f};

    // K-steps sourced from the input cache (layer 0 and the concat part of L4)
#pragma unroll 2
    for (int s = 0; s < KS_IN; ++s) {
        half8 a[4]; a_frags(Wp, gbase + s, wv, lane, a);
        half8 b[8]; b_frags(inL, 64, s * 4, ln, q, b);
        mfma_step(a, b, acc);
    }
    // K-steps sourced from the activation buffer
#pragma unroll 2
    for (int s = 0; s < KS - KS_IN; ++s) {
        half8 a[4]; a_frags(Wp, gbase + KS_IN + s, wv, lane, a);
        half8 b[8]; b_frags(actL, 256, s * 4, ln, q, b);
        mfma_step(a, b, acc);
    }

    // bias: feature = 64*wv + 16*mt + 4*q + r  (matches C/D row = q*4 + r)
    floatx4 bv[4];
#pragma unroll
    for (int mt = 0; mt < 4; ++mt)
        bv[mt] = *(const floatx4*)(bias + wv * 64 + mt * 16 + q * 4);

    if (!LAST) __syncthreads();   // all waves done reading actL before overwrite

#pragma unroll
    for (int mt = 0; mt < 4; ++mt) {
#pragma unroll
        for (int nt = 0; nt < 8; ++nt) {
            floatx4 v = acc[mt][nt];
            v.x += bv[mt].x; v.y += bv[mt].y; v.z += bv[mt].z; v.w += bv[mt].w;
            if (RELU) {
                v.x = fmaxf(v.x, 0.f); v.y = fmaxf(v.y, 0.f);
                v.z = fmaxf(v.z, 0.f); v.w = fmaxf(v.w, 0.f);
            }
            if (LAST) {
                size_t p = (size_t)(pbase + nt * 16 + ln);
                *(floatx4*)(out + p * 256 + wv * 64 + mt * 16 + q * 4) = v;
            } else {
                half4 h = { (_Float16)v.x, (_Float16)v.y, (_Float16)v.z, (_Float16)v.w };
                int c  = wv * 8 + mt * 2 + (q >> 1);     // 16B chunk = feature>>3
                int ch = c ^ (ln & 7);                   // XOR swizzle by point&7
                *(half4*)(actL + (nt * 16 + ln) * 256 + ch * 8 + (q & 1) * 4) = h;
            }
        }
    }
    if (!LAST) __syncthreads();
}

__global__ void __launch_bounds__(256, 2) mlp_main(
    const float* __restrict__ in, const _Float16* __restrict__ Wp,
    const float* __restrict__ b0, const float* __restrict__ b1,
    const float* __restrict__ b2, const float* __restrict__ b3,
    const float* __restrict__ b4, const float* __restrict__ b5,
    const float* __restrict__ b6, const float* __restrict__ b7,
    float* __restrict__ out)
{
    __shared__ __align__(16) _Float16 actL[128 * 256];  // 64 KB, [point][feat] swizzled
    __shared__ __align__(16) _Float16 inL [128 * 64];   // 16 KB, input cache (K padded to 64)

    const int t = threadIdx.x;
    const int wv = t >> 6, lane = t & 63;
    const int pbase = blockIdx.x * P_TILE;

    // Stage input tile: 128 points x 64 (63 real + 1 zero pad), f16, swizzled.
#pragma unroll 4
    for (int idx = t; idx < 128 * 64; idx += 256) {
        int p = idx >> 6, f = idx & 63;
        float v = (f < IN_DIM) ? in[(size_t)(pbase + p) * IN_DIM + f] : 0.f;
        inL[p * 64 + (((f >> 3) ^ (p & 7)) << 3) + (f & 7)] = (_Float16)v;
    }
    __syncthreads();

    layer_fn< 2, 2, true,  false>(Wp,  0, b0, inL, actL, out, pbase, wv, lane);
    layer_fn< 8, 0, true,  false>(Wp,  2, b1, inL, actL, out, pbase, wv, lane);
    layer_fn< 8, 0, true,  false>(Wp, 10, b2, inL, actL, out, pbase, wv, lane);
    layer_fn< 8, 0, true,  false>(Wp, 18, b3, inL, actL, out, pbase, wv, lane);
    layer_fn<10, 2, true,  false>(Wp, 26, b4, inL, actL, out, pbase, wv, lane);
    layer_fn< 8, 0, true,  false>(Wp, 36, b5, inL, actL, out, pbase, wv, lane);
    layer_fn< 8, 0, true,  false>(Wp, 44, b6, inL, actL, out, pbase, wv, lane);
    layer_fn< 8, 0, false, true >(Wp, 52, b7, inL, actL, out, pbase, wv, lane);
}

// ---------------- launch -----------------------------------------------------
extern "C" void kernel_launch(void* const* d_in, const int* in_sizes, int n_in,
                              void* d_out, int out_size, void* d_ws, size_t ws_size,
                              hipStream_t stream)
{
    const float* in = (const float*)d_in[0];
    const float* W[8]; const float* B[8];
    for (int i = 0; i < 8; ++i) {
        W[i] = (const float*)d_in[1 + 2 * i];
        B[i] = (const float*)d_in[2 + 2 * i];
    }
    _Float16* Wp = (_Float16*)d_ws;   // needs 60*16*512*2 = 983040 bytes

    hipLaunchKernelGGL(mlp_prep, dim3(1920), dim3(256), 0, stream,
                       Wp, W[0], W[1], W[2], W[3], W[4], W[5], W[6], W[7]);
    hipLaunchKernelGGL(mlp_main, dim3(N_BLOCKS), dim3(256), 0, stream,
                       in, Wp, B[0], B[1], B[2], B[3], B[4], B[5], B[6], B[7],
                       (float*)d_out);
}

// Round 2
// 1031.366 us; speedup vs baseline: 1.0963x; 1.0963x over previous
//
#include <hip/hip_runtime.h>
#include <cstddef>

// Fused 8-layer MLP (NeRF-style), MI355X gfx950. Round 1.
// R1 change: 64-point tiles -> LDS 40KB (act 32K + in 8K) = 4 blocks/CU
// (16 waves/CU, 4/SIMD vs 2 before), acc per wave 4x4 tiles (64 VGPRs),
// __launch_bounds__(256,4) to cap regs at 128, explicit a-frag prefetch
// one k-step ahead. Goal: hide LDS/L2 latency + barrier drains with TLP.

typedef _Float16 half8 __attribute__((ext_vector_type(8)));
typedef _Float16 half4 __attribute__((ext_vector_type(4)));
typedef float floatx4 __attribute__((ext_vector_type(4)));

#define N_POINTS 524288
#define IN_DIM   63
#define P_TILE   64
#define N_BLOCKS (N_POINTS / P_TILE)   // 8192

// KS per layer: L0=2 (K=64 padded), L1..3=8, L4=10 (K=320 padded), L5..7=8.
// cum bases: 0,2,10,18,26,36,44,52 (60 ksteps total; 60*16*512 halfs)

// ---------------- prep: pack weights into A-fragment order, f16 -------------
// Wp[((gks*16 + mt)*64 + lane)*8 + i] = W_l[k][m],
// m = 16*mt + (lane&15), k = 32*(gks-cum_l) + (lane>>4)*8 + i.
__global__ void mlp_prep(_Float16* __restrict__ Wp,
    const float* __restrict__ W0, const float* __restrict__ W1,
    const float* __restrict__ W2, const float* __restrict__ W3,
    const float* __restrict__ W4, const float* __restrict__ W5,
    const float* __restrict__ W6, const float* __restrict__ W7)
{
    int e    = blockIdx.x * 256 + threadIdx.x;   // 0 .. 491519
    int gks  = e >> 13;
    int rem  = e & 8191;
    int mt   = rem >> 9;
    int r3   = rem & 511;
    int lane = r3 >> 3;
    int i    = r3 & 7;
    int m    = mt * 16 + (lane & 15);

    int l, kb;
    if      (gks <  2) { l = 0; kb = gks;      }
    else if (gks < 10) { l = 1; kb = gks - 2;  }
    else if (gks < 18) { l = 2; kb = gks - 10; }
    else if (gks < 26) { l = 3; kb = gks - 18; }
    else if (gks < 36) { l = 4; kb = gks - 26; }
    else if (gks < 44) { l = 5; kb = gks - 36; }
    else if (gks < 52) { l = 6; kb = gks - 44; }
    else               { l = 7; kb = gks - 52; }
    int k = kb * 32 + (lane >> 4) * 8 + i;

    const float* W = (l==0)?W0:(l==1)?W1:(l==2)?W2:(l==3)?W3:(l==4)?W4:(l==5)?W5:(l==6)?W6:W7;
    float v;
    if (l == 0)      v = (k < IN_DIM) ? W[k * 256 + m] : 0.f;
    else if (l == 4) v = (k < IN_DIM) ? W[k * 256 + m]
                        : (k == IN_DIM ? 0.f : W[(k - 1) * 256 + m]);
    else             v = W[k * 256 + m];
    Wp[e] = (_Float16)v;
}

// ---------------- main fused kernel -----------------------------------------
__device__ __forceinline__ void a_frags(const _Float16* __restrict__ Wp,
                                        int gks, int wv, int lane, half8 (&a)[4])
{
    const _Float16* base = Wp + ((size_t)gks * 16 + (size_t)wv * 4) * 512 + lane * 8;
#pragma unroll
    for (int mt = 0; mt < 4; ++mt)
        a[mt] = *(const half8*)(base + mt * 512);
}

// B frags from LDS. rowHalfs = 64 (input cache) or 256 (activations).
// 16B chunk index = (cbase + q) ^ (point & 7); rows are bank-aligned so the
// XOR spreads the 8 bank-groups; the ln/ln+8 2-way alias is free (m136).
__device__ __forceinline__ void b_frags(const _Float16* __restrict__ src,
                                        int rowHalfs, int cbase, int ln, int q,
                                        half8 (&b)[4])
{
    int ch = ((cbase + q) ^ (ln & 7)) << 3;
    const _Float16* base = src + ln * rowHalfs + ch;
    int step = 16 * rowHalfs;
#pragma unroll
    for (int nt = 0; nt < 4; ++nt)
        b[nt] = *(const half8*)(base + nt * step);
}

template<int KS, int KS_IN, bool RELU, bool LAST>
__device__ __forceinline__ void layer_fn(const _Float16* __restrict__ Wp, int gbase,
                                         const float* __restrict__ bias,
                                         const _Float16* __restrict__ inL,
                                         _Float16* __restrict__ actL,
                                         float* __restrict__ out, int pbase,
                                         int wv, int lane)
{
    const int ln = lane & 15, q = lane >> 4;
    floatx4 acc[4][4];
#pragma unroll
    for (int mt = 0; mt < 4; ++mt)
#pragma unroll
        for (int nt = 0; nt < 4; ++nt)
            acc[mt][nt] = (floatx4){0.f, 0.f, 0.f, 0.f};

    // software-pipeline the (global, ~L2-latency) a-frag loads one step ahead
    half8 a_cur[4], a_nxt[4];
    a_frags(Wp, gbase, wv, lane, a_cur);

#pragma unroll 2
    for (int s = 0; s < KS; ++s) {
        int sn = (s + 1 < KS) ? s + 1 : s;          // clamp: harmless reload
        a_frags(Wp, gbase + sn, wv, lane, a_nxt);

        half8 b[4];
        if (s < KS_IN) b_frags(inL, 64, s * 4, ln, q, b);
        else           b_frags(actL, 256, (s - KS_IN) * 4, ln, q, b);

#pragma unroll
        for (int nt = 0; nt < 4; ++nt)
#pragma unroll
            for (int mt = 0; mt < 4; ++mt)
                acc[mt][nt] = __builtin_amdgcn_mfma_f32_16x16x32_f16(a_cur[mt], b[nt], acc[mt][nt], 0, 0, 0);

#pragma unroll
        for (int mt = 0; mt < 4; ++mt) a_cur[mt] = a_nxt[mt];
    }

    // bias: feature = 64*wv + 16*mt + 4*q + r  (C/D row = q*4 + r)
    floatx4 bv[4];
#pragma unroll
    for (int mt = 0; mt < 4; ++mt)
        bv[mt] = *(const floatx4*)(bias + wv * 64 + mt * 16 + q * 4);

    if (!LAST) __syncthreads();   // all waves done reading actL before overwrite

#pragma unroll
    for (int mt = 0; mt < 4; ++mt) {
#pragma unroll
        for (int nt = 0; nt < 4; ++nt) {
            floatx4 v = acc[mt][nt];
            v.x += bv[mt].x; v.y += bv[mt].y; v.z += bv[mt].z; v.w += bv[mt].w;
            if (RELU) {
                v.x = fmaxf(v.x, 0.f); v.y = fmaxf(v.y, 0.f);
                v.z = fmaxf(v.z, 0.f); v.w = fmaxf(v.w, 0.f);
            }
            if (LAST) {
                size_t p = (size_t)(pbase + nt * 16 + ln);
                *(floatx4*)(out + p * 256 + wv * 64 + mt * 16 + q * 4) = v;
            } else {
                half4 h = { (_Float16)v.x, (_Float16)v.y, (_Float16)v.z, (_Float16)v.w };
                int c  = wv * 8 + mt * 2 + (q >> 1);     // 16B chunk = feature>>3
                int ch = c ^ (ln & 7);                   // XOR swizzle by point&7
                *(half4*)(actL + (nt * 16 + ln) * 256 + ch * 8 + (q & 1) * 4) = h;
            }
        }
    }
    if (!LAST) __syncthreads();
}

__global__ void __launch_bounds__(256, 4) mlp_main(
    const float* __restrict__ in, const _Float16* __restrict__ Wp,
    const float* __restrict__ b0, const float* __restrict__ b1,
    const float* __restrict__ b2, const float* __restrict__ b3,
    const float* __restrict__ b4, const float* __restrict__ b5,
    const float* __restrict__ b6, const float* __restrict__ b7,
    float* __restrict__ out)
{
    __shared__ __align__(16) _Float16 actL[P_TILE * 256];  // 32 KB
    __shared__ __align__(16) _Float16 inL [P_TILE * 64];   // 8 KB

    const int t = threadIdx.x;
    const int wv = t >> 6, lane = t & 63;
    const int pbase = blockIdx.x * P_TILE;

    // Stage input tile: 64 points x 64 (63 real + 1 zero pad), f16, swizzled.
#pragma unroll 4
    for (int idx = t; idx < P_TILE * 64; idx += 256) {
        int p = idx >> 6, f = idx & 63;
        float v = (f < IN_DIM) ? in[(size_t)(pbase + p) * IN_DIM + f] : 0.f;
        inL[p * 64 + (((f >> 3) ^ (p & 7)) << 3) + (f & 7)] = (_Float16)v;
    }
    __syncthreads();

    layer_fn< 2, 2, true,  false>(Wp,  0, b0, inL, actL, out, pbase, wv, lane);
    layer_fn< 8, 0, true,  false>(Wp,  2, b1, inL, actL, out, pbase, wv, lane);
    layer_fn< 8, 0, true,  false>(Wp, 10, b2, inL, actL, out, pbase, wv, lane);
    layer_fn< 8, 0, true,  false>(Wp, 18, b3, inL, actL, out, pbase, wv, lane);
    layer_fn<10, 2, true,  false>(Wp, 26, b4, inL, actL, out, pbase, wv, lane);
    layer_fn< 8, 0, true,  false>(Wp, 36, b5, inL, actL, out, pbase, wv, lane);
    layer_fn< 8, 0, true,  false>(Wp, 44, b6, inL, actL, out, pbase, wv, lane);
    layer_fn< 8, 0, false, true >(Wp, 52, b7, inL, actL, out, pbase, wv, lane);
}

// ---------------- launch -----------------------------------------------------
extern "C" void kernel_launch(void* const* d_in, const int* in_sizes, int n_in,
                              void* d_out, int out_size, void* d_ws, size_t ws_size,
                              hipStream_t stream)
{
    const float* in = (const float*)d_in[0];
    const float* W[8]; const float* B[8];
    for (int i = 0; i < 8; ++i) {
        W[i] = (const float*)d_in[1 + 2 * i];
        B[i] = (const float*)d_in[2 + 2 * i];
    }
    _Float16* Wp = (_Float16*)d_ws;   // 60*16*512*2 = 983040 bytes

    hipLaunchKernelGGL(mlp_prep, dim3(1920), dim3(256), 0, stream,
                       Wp, W[0], W[1], W[2], W[3], W[4], W[5], W[6], W[7]);
    hipLaunchKernelGGL(mlp_main, dim3(N_BLOCKS), dim3(256), 0, stream,
                       in, Wp, B[0], B[1], B[2], B[3], B[4], B[5], B[6], B[7],
                       (float*)d_out);
}